// Round 13
// baseline (250.414 us; speedup 1.0000x reference)
//
#include <hip/hip_runtime.h>

// MHA forward: B=2, S=2048, D=1024, H=16, HD=64. Inputs f32, mask int32,
// OUTPUT f32. Intermediates bf16.
//
// Round 21: rehabilitate R16's T3/T4 GEMM pipeline with R17's clean epilogue.
//   R16 (raw-barrier + counted-vmcnt reg pipeline) measured 172us but with
//   360MB WRITE amplification from the old scattered epilogue (~57us of pure
//   HBM writes) -- the pipeline itself was never tested with line-friendly
//   stores. R17 fixed writes to 24MB logical (64.7us) but on the stalling
//   2-sync dma16 loop. This round combines them:
//  - gemm_qkv_t34: 2-deep reg-staged pipeline, ONE raw bar()/tile (lgkmcnt(0)
//    + s_barrier, NO vmcnt drain -> prefetch loads span barriers, compiler
//    emits counted vmcnt at STORES), wa epilogue (32B+ contiguous stores),
//    swizzled LDS write/read (R19, verified). Grid (32,8,3) = 3 blk/CU.
//  - gemm_proj_t34: same loop, 128x128, full-line f32 stores. Grid (32,8).
//  - attn: R20 (paired q-tiles, 55.5us) minus the no-op fminf clamps
//    (logits bounded in log2 domain -> pure VALU cut).

#define BB 2
#define SS 2048
#define DD 1024
#define HH 16
#define HDD 64
#define NEG_BIG (-1.0e30f)
#define QSCL 0.18033688011112042f  // 0.125 * log2(e)

typedef __attribute__((ext_vector_type(8))) short short8;
typedef __attribute__((ext_vector_type(4))) float floatx4;
typedef unsigned int u32;
#define AS_GLOBAL __attribute__((address_space(1)))
#define AS_LDS    __attribute__((address_space(3)))

__device__ __forceinline__ ushort f2bf(float f) {  // RNE
    unsigned u = __float_as_uint(f);
    u += 0x7fffu + ((u >> 16) & 1u);
    return (ushort)(u >> 16);
}
__device__ __forceinline__ unsigned pk2(float a, float b) {
    return ((unsigned)f2bf(b) << 16) | (unsigned)f2bf(a);
}
__device__ __forceinline__ unsigned cvtpk(float a, float b) {  // lo=a, hi=b, RNE
    unsigned r;
    asm("v_cvt_pk_bf16_f32 %0, %1, %2" : "=v"(r) : "v"(a), "v"(b));
    return r;
}
__device__ __forceinline__ void unpack8(const uint4 u, float* d) {
    d[0] = __uint_as_float(u.x << 16);
    d[1] = __uint_as_float(u.x & 0xffff0000u);
    d[2] = __uint_as_float(u.y << 16);
    d[3] = __uint_as_float(u.y & 0xffff0000u);
    d[4] = __uint_as_float(u.z << 16);
    d[5] = __uint_as_float(u.z & 0xffff0000u);
    d[6] = __uint_as_float(u.w << 16);
    d[7] = __uint_as_float(u.w & 0xffff0000u);
}
__device__ __forceinline__ void dma16(void* lds, const void* g) {
    __builtin_amdgcn_global_load_lds((const AS_GLOBAL u32*)g, (AS_LDS u32*)lds,
                                     16, 0, 0);
}
// Raw barrier: lgkmcnt(0) makes our LDS writes visible; s_barrier WITHOUT a
// vmcnt drain -> in-flight global loads survive the barrier (T4).
__device__ __forceinline__ void bar() {
    asm volatile("s_waitcnt lgkmcnt(0)" ::: "memory");
    __builtin_amdgcn_s_barrier();
    asm volatile("" ::: "memory");
}

// ---------------- f32 -> bf16 conversion (x, Wq, Wk, Wv, Wp) ----------------
__global__ __launch_bounds__(256) void cvt_all(
    const float* __restrict__ x, const float* __restrict__ wq,
    const float* __restrict__ wk, const float* __restrict__ wv,
    const float* __restrict__ wp,
    ushort* __restrict__ dst, ushort* __restrict__ wp_dst)
{
    const size_t flat = ((size_t)blockIdx.x * 256 + threadIdx.x) * 8;
    const float* s;
    ushort* d = dst + flat;
    size_t off;
    float scl = 1.0f;
    if (flat < (size_t)4194304)      { s = x;  off = flat; }
    else if (flat < (size_t)5242880) { s = wq; off = flat - 4194304; scl = QSCL; }
    else if (flat < (size_t)6291456) { s = wk; off = flat - 5242880; }
    else if (flat < (size_t)7340032) { s = wv; off = flat - 6291456; }
    else { s = wp; off = flat - 7340032; d = wp_dst + off; }
    const float4 a = ((const float4*)(s + off))[0];
    const float4 b = ((const float4*)(s + off))[1];
    uint4 u;
    u.x = pk2(a.x * scl, a.y * scl); u.y = pk2(a.z * scl, a.w * scl);
    u.z = pk2(b.x * scl, b.y * scl); u.w = pk2(b.z * scl, b.w * scl);
    *(uint4*)d = u;
}

// ---------------- QKV GEMM: T3/T4 pipeline + wa epilogue -------------------
// z=0: Q (swapped, bias*QSCL, out (B,H,S,HD))
// z=1: K (swapped, out (B,H,S,HD))
// z=2: V (unswapped, out (B,H,HD,S))
__global__ __launch_bounds__(256, 3) void gemm_qkv_t34(
    const ushort* __restrict__ A,
    const ushort* __restrict__ W0, const ushort* __restrict__ W1,
    const ushort* __restrict__ W2,
    const float* __restrict__ B0, const float* __restrict__ B1,
    const float* __restrict__ B2,
    ushort* __restrict__ O0, ushort* __restrict__ O1, ushort* __restrict__ O2)
{
    __shared__ ushort As[2][128 * 32];
    __shared__ ushort Bs[2][128 * 32];
    __shared__ float bias_s[128];

    const int z = blockIdx.z;
    const ushort* W = (z == 0) ? W0 : (z == 1 ? W1 : W2);
    const float* bias = (z == 0) ? B0 : (z == 1 ? B1 : B2);
    ushort* out = (z == 0) ? O0 : (z == 1 ? O1 : O2);
    const bool isv = (z == 2);

    const int tid = threadIdx.x;
    const int bm = blockIdx.x * 128, bn = blockIdx.y * 128;
    const int wave = tid >> 6, lane = tid & 63, quad = lane >> 4, lm = lane & 15;
    const int r0 = tid >> 2, c0 = (tid & 3) * 8;
    const int c0s = ((tid & 3) ^ ((tid >> 3) & 3)) * 8;   // swizzled LDS chunk
    const int csw8 = (quad ^ ((lm >> 1) & 3)) * 8;        // swizzled read chunk

    if (tid < 128) {
        float bb = bias[bn + tid];
        if (z == 0) bb *= QSCL;
        bias_s[tid] = bb;
    }

    const floatx4 zz = {0.f, 0.f, 0.f, 0.f};
    floatx4 acc[16];
#pragma unroll
    for (int i = 0; i < 16; ++i) acc[i] = zz;

    const ushort* ap = A + (size_t)(bm + r0) * DD + c0;
    const ushort* wpp = W + (size_t)(bn + r0) * DD + c0;

    uint4 pA0, pA1, pA2, pA3, pB0, pB1, pB2, pB3;

#define LOADS(s, K0)                                              \
    do {                                                          \
        s##0 = *(const uint4*)(ap + (K0));                        \
        s##1 = *(const uint4*)(ap + (size_t)64 * DD + (K0));      \
        s##2 = *(const uint4*)(wpp + (K0));                       \
        s##3 = *(const uint4*)(wpp + (size_t)64 * DD + (K0));     \
    } while (0)
#define STORES(buf, s)                                            \
    do {                                                          \
        *(uint4*)&As[buf][r0 * 32 + c0s] = s##0;                  \
        *(uint4*)&As[buf][(64 + r0) * 32 + c0s] = s##1;           \
        *(uint4*)&Bs[buf][r0 * 32 + c0s] = s##2;                  \
        *(uint4*)&Bs[buf][(64 + r0) * 32 + c0s] = s##3;           \
    } while (0)
#define COMPUTE(buf)                                                          \
    do {                                                                      \
        if (isv) {                                                            \
            const short8 bf0 = *(const short8*)&Bs[buf][(wave * 32 + lm) * 32 + csw8];      \
            const short8 bf1 = *(const short8*)&Bs[buf][(wave * 32 + 16 + lm) * 32 + csw8]; \
            _Pragma("unroll")                                                 \
            for (int i = 0; i < 8; ++i) {                                     \
                const short8 af = *(const short8*)&As[buf][(i * 16 + lm) * 32 + csw8];      \
                acc[i * 2 + 0] = __builtin_amdgcn_mfma_f32_16x16x32_bf16(     \
                    af, bf0, acc[i * 2 + 0], 0, 0, 0);                        \
                acc[i * 2 + 1] = __builtin_amdgcn_mfma_f32_16x16x32_bf16(     \
                    af, bf1, acc[i * 2 + 1], 0, 0, 0);                        \
            }                                                                 \
        } else {                                                              \
            const short8 af0 = *(const short8*)&As[buf][(wave * 32 + lm) * 32 + csw8];      \
            const short8 af1 = *(const short8*)&As[buf][(wave * 32 + 16 + lm) * 32 + csw8]; \
            _Pragma("unroll")                                                 \
            for (int j = 0; j < 8; ++j) {                                     \
                const short8 bf = *(const short8*)&Bs[buf][(j * 16 + lm) * 32 + csw8];      \
                acc[j] = __builtin_amdgcn_mfma_f32_16x16x32_bf16(             \
                    bf, af0, acc[j], 0, 0, 0);                                \
                acc[8 + j] = __builtin_amdgcn_mfma_f32_16x16x32_bf16(         \
                    bf, af1, acc[8 + j], 0, 0, 0);                            \
            }                                                                 \
        }                                                                     \
    } while (0)

    // prologue: tile0 staged; tile1 in flight
    LOADS(pA, 0);
    STORES(0, pA);   // vmcnt(0) once
    bar();
    LOADS(pA, 32);   // tile1 in flight across barriers

    for (int k0 = 0; k0 < DD; k0 += 64) {
        if (k0 + 64 < DD) LOADS(pB, k0 + 64);   // tile+2 in flight
        COMPUTE(0);
        STORES(1, pA);                          // counted vmcnt (pB newer)
        bar();
        if (k0 + 96 < DD) LOADS(pA, k0 + 96);   // tile+3 in flight
        COMPUTE(1);
        if (k0 + 64 < DD) STORES(0, pB);        // counted vmcnt (pA newer)
        bar();
    }
#undef LOADS
#undef STORES
#undef COMPUTE

    if (isv) {
        // V: n-row per lane, 4 consecutive s per reg; 32B contiguous/instr.
        const int b = bm >> 11, sbase = bm & 2047;
#pragma unroll
        for (int j = 0; j < 2; ++j) {
            const int n = bn + wave * 32 + j * 16 + lm;
            const float bb = bias_s[n - bn];
            ushort* orow = out + ((size_t)(b * DD + n)) * SS;
#pragma unroll
            for (int i = 0; i < 8; ++i) {
                const floatx4 a = acc[i * 2 + j];
                ushort4 v;
                v.x = f2bf(a[0] + bb); v.y = f2bf(a[1] + bb);
                v.z = f2bf(a[2] + bb); v.w = f2bf(a[3] + bb);
                *(ushort4*)(orow + sbase + i * 16 + quad * 4) = v;
            }
        }
    } else {
        // Q/K: m-row per lane, 4 consecutive hd per reg; 32B contiguous/instr.
#pragma unroll
        for (int i = 0; i < 2; ++i) {
            const int m = bm + wave * 32 + i * 16 + lm;
            const int b = m >> 11, s = m & 2047;
#pragma unroll
            for (int j = 0; j < 8; ++j) {
                const int nl = j * 16 + quad * 4;
                const int n = bn + nl;
                const int h = n >> 6, hd = n & 63;
                const floatx4 a = acc[i * 8 + j];
                ushort4 v;
                v.x = f2bf(a[0] + bias_s[nl + 0]);
                v.y = f2bf(a[1] + bias_s[nl + 1]);
                v.z = f2bf(a[2] + bias_s[nl + 2]);
                v.w = f2bf(a[3] + bias_s[nl + 3]);
                *(ushort4*)(out + (((size_t)(b * HH + h) * SS) + s) * HDD + hd) = v;
            }
        }
    }
}

// ---------------- proj GEMM: 128x128, T3/T4 pipeline, f32 out --------------
__global__ __launch_bounds__(256, 2) void gemm_proj_t34(
    const ushort* __restrict__ A, const ushort* __restrict__ W,
    const float* __restrict__ bias, float* __restrict__ out)
{
    __shared__ ushort As[2][128 * 32];
    __shared__ ushort Bs[2][128 * 32];
    __shared__ float bias_s[128];

    const int tid = threadIdx.x;
    const int bm = blockIdx.x * 128, bn = blockIdx.y * 128;
    const int wave = tid >> 6, lane = tid & 63, quad = lane >> 4, lm = lane & 15;
    const int wm = wave >> 1, wn = wave & 1;
    const int r0 = tid >> 2, c0 = (tid & 3) * 8;
    const int c0s = ((tid & 3) ^ ((tid >> 3) & 3)) * 8;
    const int csw8 = (quad ^ ((lm >> 1) & 3)) * 8;

    if (tid < 128) bias_s[tid] = bias[bn + tid];

    const floatx4 zz = {0.f, 0.f, 0.f, 0.f};
    floatx4 acc[4][4];
#pragma unroll
    for (int i = 0; i < 4; ++i)
#pragma unroll
        for (int j = 0; j < 4; ++j) acc[i][j] = zz;

    const ushort* ap = A + (size_t)(bm + r0) * DD + c0;
    const ushort* wpp = W + (size_t)(bn + r0) * DD + c0;

    uint4 pA0, pA1, pA2, pA3, pB0, pB1, pB2, pB3;

#define LOADS(s, K0)                                              \
    do {                                                          \
        s##0 = *(const uint4*)(ap + (K0));                        \
        s##1 = *(const uint4*)(ap + (size_t)64 * DD + (K0));      \
        s##2 = *(const uint4*)(wpp + (K0));                       \
        s##3 = *(const uint4*)(wpp + (size_t)64 * DD + (K0));     \
    } while (0)
#define STORES(buf, s)                                            \
    do {                                                          \
        *(uint4*)&As[buf][r0 * 32 + c0s] = s##0;                  \
        *(uint4*)&As[buf][(64 + r0) * 32 + c0s] = s##1;           \
        *(uint4*)&Bs[buf][r0 * 32 + c0s] = s##2;                  \
        *(uint4*)&Bs[buf][(64 + r0) * 32 + c0s] = s##3;           \
    } while (0)
#define COMPUTE(buf)                                                          \
    do {                                                                      \
        short8 af[4], bf[4];                                                  \
        _Pragma("unroll")                                                     \
        for (int i = 0; i < 4; ++i)                                           \
            af[i] = *(const short8*)&As[buf][(wm * 64 + i * 16 + lm) * 32 + csw8]; \
        _Pragma("unroll")                                                     \
        for (int j = 0; j < 4; ++j)                                           \
            bf[j] = *(const short8*)&Bs[buf][(wn * 64 + j * 16 + lm) * 32 + csw8]; \
        _Pragma("unroll")                                                     \
        for (int i = 0; i < 4; ++i)                                           \
            _Pragma("unroll")                                                 \
            for (int j = 0; j < 4; ++j)                                       \
                acc[i][j] = __builtin_amdgcn_mfma_f32_16x16x32_bf16(          \
                    bf[j], af[i], acc[i][j], 0, 0, 0);                        \
    } while (0)

    LOADS(pA, 0);
    STORES(0, pA);
    bar();
    LOADS(pA, 32);

    for (int k0 = 0; k0 < DD; k0 += 64) {
        if (k0 + 64 < DD) LOADS(pB, k0 + 64);
        COMPUTE(0);
        STORES(1, pA);
        bar();
        if (k0 + 96 < DD) LOADS(pA, k0 + 96);
        COMPUTE(1);
        if (k0 + 64 < DD) STORES(0, pB);
        bar();
    }
#undef LOADS
#undef STORES
#undef COMPUTE

#pragma unroll
    for (int i = 0; i < 4; ++i) {
#pragma unroll
        for (int j = 0; j < 4; ++j) {
            const int nl = wn * 64 + j * 16 + quad * 4;
            const int n = bn + nl;
            const int m = bm + wm * 64 + i * 16 + lm;
            float4 v;
            v.x = acc[i][j][0] + bias_s[nl + 0];
            v.y = acc[i][j][1] + bias_s[nl + 1];
            v.z = acc[i][j][2] + bias_s[nl + 2];
            v.w = acc[i][j][3] + bias_s[nl + 3];
            *(float4*)(out + (size_t)m * DD + n) = v;
        }
    }
}

// ---------------- Attention: uniform-work paired q-tiles, split-K x2 -------
__global__ __launch_bounds__(256) void attn_mfma(
    const ushort* __restrict__ Q, const ushort* __restrict__ K,
    const ushort* __restrict__ Vt, const int* __restrict__ am,
    ushort* __restrict__ Opart, float* __restrict__ lbuf)
{
    __shared__ ushort Ks[64 * 72];
    __shared__ ushort Vts[64 * 72];
    __shared__ ushort Ps[4][16 * 72];
    __shared__ int amk_s[64];

    const int tid = threadIdx.x;
    const int wq = tid >> 6, lane = tid & 63, quad = lane >> 4, lm = lane & 15;
    const int bh = blockIdx.y, b = bh >> 4, h = bh & 15;
    const int pslot = (int)blockIdx.x;   // 0..15
    const int split = (int)blockIdx.z;   // 0,1
    const size_t base = (size_t)bh * SS * HDD;
    const size_t tbase = (size_t)bh * HDD * SS;
    const int* amrow = am + b * SS;
    const int sr = tid >> 2, sc = (tid & 3) * 16;
    const floatx4 zz = {0.f, 0.f, 0.f, 0.f};

#pragma unroll
    for (int ph = 0; ph < 2; ++ph) {
        const int qt64 = ph ? (31 - pslot) : pslot;
        const int q0 = qt64 * 64;
        const int ktend = qt64;          // causal: kt*64 <= q0+63
        const int qrow = q0 + wq * 16 + lm;

        if (ph) __syncthreads();  // phase A LDS reads done before B staging

        short8 qf0, qf1;
        {
            const ushort* qp = Q + base + (size_t)qrow * HDD + quad * 8;
            qf0 = *(const short8*)qp;
            qf1 = *(const short8*)(qp + 32);
        }
        const int amq = amrow[qrow];
        const bool allq = __all(amq != 0);

        floatx4 o_acc[4];
#pragma unroll
        for (int n2 = 0; n2 < 4; ++n2) o_acc[n2] = zz;
        float l_lane = 0.f;

        if (split <= ktend) {
            // ---- prologue: stage first tile ----
            uint4 kra, krb, vra, vrb;
            int amr = 1;
            {
                const ushort* kp = K + base + (size_t)(split * 64 + sr) * HDD + sc;
                kra = ((const uint4*)kp)[0]; krb = ((const uint4*)kp)[1];
                const ushort* vp = Vt + tbase + (size_t)sr * SS + split * 64 + sc;
                vra = ((const uint4*)vp)[0]; vrb = ((const uint4*)vp)[1];
                if (tid < 64) amr = amrow[split * 64 + tid];
            }
            *(uint4*)&Ks[sr * 72 + sc] = kra;
            *(uint4*)&Ks[sr * 72 + sc + 8] = krb;
            *(uint4*)&Vts[sr * 72 + sc] = vra;
            *(uint4*)&Vts[sr * 72 + sc + 8] = vrb;
            if (tid < 64) amk_s[tid] = amr;
            __syncthreads();

            for (int kt = split; kt <= ktend; kt += 2) {
                const int nxt = kt + 2;
                const bool have_nxt = nxt <= ktend;
                // T14: issue next tile's global loads; LDS writes after barrier.
                if (have_nxt) {
                    const ushort* kp = K + base + (size_t)(nxt * 64 + sr) * HDD + sc;
                    kra = ((const uint4*)kp)[0]; krb = ((const uint4*)kp)[1];
                    const ushort* vp = Vt + tbase + (size_t)sr * SS + nxt * 64 + sc;
                    vra = ((const uint4*)vp)[0]; vrb = ((const uint4*)vp)[1];
                    if (tid < 64) amr = amrow[nxt * 64 + tid];
                }

                // ---- S^T = K Q^T (swapped): regs = 4 consecutive t ----
                const bool allk = (__ballot(amk_s[lane] != 0) == ~0ull);
                const bool fast = allk & allq & ((kt * 64 + 63) <= (q0 + wq * 16));
                if (fast) {
#pragma unroll
                    for (int nt = 0; nt < 4; ++nt) {
                        const short8 kf0 = *(const short8*)&Ks[(nt * 16 + lm) * 72 + quad * 8];
                        const short8 kf1 = *(const short8*)&Ks[(nt * 16 + lm) * 72 + 32 + quad * 8];
                        floatx4 s = zz;
                        s = __builtin_amdgcn_mfma_f32_16x16x32_bf16(kf0, qf0, s, 0, 0, 0);
                        s = __builtin_amdgcn_mfma_f32_16x16x32_bf16(kf1, qf1, s, 0, 0, 0);
                        const float e0 = exp2f(s[0]);
                        const float e1 = exp2f(s[1]);
                        const float e2 = exp2f(s[2]);
                        const float e3 = exp2f(s[3]);
                        l_lane += (e0 + e1) + (e2 + e3);
                        uint2 pv;
                        pv.x = cvtpk(e0, e1); pv.y = cvtpk(e2, e3);
                        *(uint2*)&Ps[wq][lm * 72 + nt * 16 + quad * 4] = pv;
                    }
                } else {
#pragma unroll
                    for (int nt = 0; nt < 4; ++nt) {
                        const short8 kf0 = *(const short8*)&Ks[(nt * 16 + lm) * 72 + quad * 8];
                        const short8 kf1 = *(const short8*)&Ks[(nt * 16 + lm) * 72 + 32 + quad * 8];
                        const int4 amk4 = *(const int4*)&amk_s[nt * 16 + quad * 4];
                        floatx4 s = zz;
                        s = __builtin_amdgcn_mfma_f32_16x16x32_bf16(kf0, qf0, s, 0, 0, 0);
                        s = __builtin_amdgcn_mfma_f32_16x16x32_bf16(kf1, qf1, s, 0, 0, 0);
                        const int t0 = kt * 64 + nt * 16 + quad * 4;
                        const bool mq = amq != 0;
                        const bool ok0 = amk4.x && mq && (t0 + 0 <= qrow);
                        const bool ok1 = amk4.y && mq && (t0 + 1 <= qrow);
                        const bool ok2 = amk4.z && mq && (t0 + 2 <= qrow);
                        const bool ok3 = amk4.w && mq && (t0 + 3 <= qrow);
                        const float e0 = exp2f(ok0 ? s[0] : NEG_BIG);
                        const float e1 = exp2f(ok1 ? s[1] : NEG_BIG);
                        const float e2 = exp2f(ok2 ? s[2] : NEG_BIG);
                        const float e3 = exp2f(ok3 ? s[3] : NEG_BIG);
                        l_lane += (e0 + e1) + (e2 + e3);
                        uint2 pv;
                        pv.x = cvtpk(e0, e1); pv.y = cvtpk(e2, e3);
                        *(uint2*)&Ps[wq][lm * 72 + nt * 16 + quad * 4] = pv;
                    }
                }

                // ---- O^T += V^T P^T (swapped): regs = 4 consecutive hd ----
                const short8 af0 = *(const short8*)&Ps[wq][lm * 72 + quad * 8];
                const short8 af1 = *(const short8*)&Ps[wq][lm * 72 + 32 + quad * 8];
#pragma unroll
                for (int n2 = 0; n2 < 4; ++n2) {
                    const short8 vf0 = *(const short8*)&Vts[(n2 * 16 + lm) * 72 + quad * 8];
                    const short8 vf1 = *(const short8*)&Vts[(n2 * 16 + lm) * 72 + 32 + quad * 8];
                    o_acc[n2] = __builtin_amdgcn_mfma_f32_16x16x32_bf16(
                        vf0, af0, o_acc[n2], 0, 0, 0);
                    o_acc[n2] = __builtin_amdgcn_mfma_f32_16x16x32_bf16(
                        vf1, af1, o_acc[n2], 0, 0, 0);
                }

                if (have_nxt) {
                    __syncthreads();  // all waves done reading Ks/Vts/amk_s
                    *(uint4*)&Ks[sr * 72 + sc] = kra;
                    *(uint4*)&Ks[sr * 72 + sc + 8] = krb;
                    *(uint4*)&Vts[sr * 72 + sc] = vra;
                    *(uint4*)&Vts[sr * 72 + sc + 8] = vrb;
                    if (tid < 64) amk_s[tid] = amr;
                    __syncthreads();  // next tile ready
                }
            }
        }

        // ---- epilogue: l reduce + unnormalized O ----
        float l = l_lane;
        l += __shfl_xor(l, 16);
        l += __shfl_xor(l, 32);
        if (quad == 0)
            lbuf[(size_t)split * (BB * HH * SS) + (size_t)bh * SS + qrow] = l;
#pragma unroll
        for (int n2 = 0; n2 < 4; ++n2) {
            uint2 v;
            v.x = cvtpk(o_acc[n2][0], o_acc[n2][1]);
            v.y = cvtpk(o_acc[n2][2], o_acc[n2][3]);
            *(uint2*)(Opart + (size_t)split * (BB * SS * DD)
                        + ((size_t)(b * SS + qrow)) * DD + h * HDD + n2 * 16 + quad * 4) = v;
        }
    }
}

// ---------------- combine: A = (O0 + O1) / (l0 + l1), bf16 ----------------
__global__ __launch_bounds__(256) void combine(
    const ushort* __restrict__ Opart, const float* __restrict__ lbuf,
    ushort* __restrict__ Aout)
{
    const size_t e = ((size_t)blockIdx.x * 256 + threadIdx.x) * 8;
    const int m = (int)(e >> 10);
    const int col = (int)(e & 1023);
    const int b = m >> 11, s = m & 2047, h = col >> 6;
    const float l = lbuf[(b * HH + h) * SS + s]
                  + lbuf[BB * HH * SS + (b * HH + h) * SS + s];
    const float inv = l > 0.f ? 1.f / l : 0.f;
    const uint4 u0 = *(const uint4*)(Opart + e);
    const uint4 u1 = *(const uint4*)(Opart + (size_t)BB * SS * DD + e);
    float f0[8], f1[8];
    unpack8(u0, f0);
    unpack8(u1, f1);
    uint4 o;
    o.x = pk2((f0[0] + f1[0]) * inv, (f0[1] + f1[1]) * inv);
    o.y = pk2((f0[2] + f1[2]) * inv, (f0[3] + f1[3]) * inv);
    o.z = pk2((f0[4] + f1[4]) * inv, (f0[5] + f1[5]) * inv);
    o.w = pk2((f0[6] + f1[6]) * inv, (f0[7] + f1[7]) * inv);
    *(uint4*)(Aout + e) = o;
}

extern "C" void kernel_launch(void* const* d_in, const int* in_sizes, int n_in,
                              void* d_out, int out_size, void* d_ws, size_t ws_size,
                              hipStream_t stream) {
    const float* x  = (const float*)d_in[0];
    const int*   am = (const int*)d_in[1];
    const float* Wq = (const float*)d_in[2];
    const float* bq = (const float*)d_in[3];
    const float* Wk = (const float*)d_in[4];
    const float* bk = (const float*)d_in[5];
    const float* Wv = (const float*)d_in[6];
    const float* bv = (const float*)d_in[7];
    const float* Wp = (const float*)d_in[8];
    const float* bp = (const float*)d_in[9];
    float* out = (float*)d_out;

    const size_t elems = (size_t)BB * HH * SS * HDD;  // 4M
    ushort* q_ws = (ushort*)d_ws;                 // Q; later combined A
    ushort* k_ws = q_ws + elems;
    ushort* v_ws = k_ws + elems;                  // V^T (B,H,HD,S)
    float*  lbuf = (float*)(v_ws + elems);        // 2 x 256 KB in a_ws slot
    ushort* wpb  = (ushort*)(lbuf + 2 * BB * HH * SS);  // bf16 Wp (2 MB)

    // d_out scratch: bf16 x (4M) + Wq/Wk/Wv (1M each); later attn partials
    ushort* xb  = (ushort*)d_out;
    ushort* wqb = xb + 4194304;
    ushort* wkb = wqb + 1048576;
    ushort* wvb = wkb + 1048576;

    cvt_all<<<4096, 256, 0, stream>>>(x, Wq, Wk, Wv, Wp, xb, wpb);

    gemm_qkv_t34<<<dim3(32, 8, 3), 256, 0, stream>>>(
        xb, wqb, wkb, wvb, bq, bk, bv, q_ws, k_ws, v_ws);

    attn_mfma<<<dim3(16, BB * HH, 2), 256, 0, stream>>>(
        q_ws, k_ws, v_ws, am, (ushort*)d_out, lbuf);

    combine<<<2048, 256, 0, stream>>>((const ushort*)d_out, lbuf, q_ws);

    gemm_proj_t34<<<dim3(32, 8), 256, 0, stream>>>(q_ws, wpb, bp, out);
}

// Round 14
// 206.110 us; speedup vs baseline: 1.2150x; 1.2150x over previous
//
#include <hip/hip_runtime.h>

// MHA forward: B=2, S=2048, D=1024, H=16, HD=64. Inputs f32, mask int32,
// OUTPUT f32. Intermediates bf16.
//
// Round 22: fix the REAL cause of reg-staged GEMM "write amplification":
//   launch_bounds(256,3) caps unified VGPR+AGPR at 170; t34 needs
//   64 AGPR(acc) + 32 VGPR(staging) + ~90 VGPR ~ 186 -> compiler silently
//   spilled staging regs to scratch = ~185MB of HBM writes per dispatch
//   (R14/R16/R21 all show VGPR_Count=84 + WRITE 210-360MB; dma16 variants
//   show 124 + 24.5MB). Fix: qkv_t34 at launch_bounds(256,2) (cap 256).
//   Grid (32,8,3) = 1.5 rounds at 2 blk/CU (uniform-duration blocks).
//  - proj: revert to proven gemm_proj_rs (R18-R20).
//  - attn: R21 (paired q-tiles, clamp-free). cvt/combine unchanged.

#define BB 2
#define SS 2048
#define DD 1024
#define HH 16
#define HDD 64
#define NEG_BIG (-1.0e30f)
#define QSCL 0.18033688011112042f  // 0.125 * log2(e)

typedef __attribute__((ext_vector_type(8))) short short8;
typedef __attribute__((ext_vector_type(4))) float floatx4;
typedef unsigned int u32;
#define AS_GLOBAL __attribute__((address_space(1)))
#define AS_LDS    __attribute__((address_space(3)))

__device__ __forceinline__ ushort f2bf(float f) {  // RNE
    unsigned u = __float_as_uint(f);
    u += 0x7fffu + ((u >> 16) & 1u);
    return (ushort)(u >> 16);
}
__device__ __forceinline__ unsigned pk2(float a, float b) {
    return ((unsigned)f2bf(b) << 16) | (unsigned)f2bf(a);
}
__device__ __forceinline__ unsigned cvtpk(float a, float b) {  // lo=a, hi=b, RNE
    unsigned r;
    asm("v_cvt_pk_bf16_f32 %0, %1, %2" : "=v"(r) : "v"(a), "v"(b));
    return r;
}
__device__ __forceinline__ void unpack8(const uint4 u, float* d) {
    d[0] = __uint_as_float(u.x << 16);
    d[1] = __uint_as_float(u.x & 0xffff0000u);
    d[2] = __uint_as_float(u.y << 16);
    d[3] = __uint_as_float(u.y & 0xffff0000u);
    d[4] = __uint_as_float(u.z << 16);
    d[5] = __uint_as_float(u.z & 0xffff0000u);
    d[6] = __uint_as_float(u.w << 16);
    d[7] = __uint_as_float(u.w & 0xffff0000u);
}
__device__ __forceinline__ void dma16(void* lds, const void* g) {
    __builtin_amdgcn_global_load_lds((const AS_GLOBAL u32*)g, (AS_LDS u32*)lds,
                                     16, 0, 0);
}
// Raw barrier: lgkmcnt(0) makes our LDS writes visible; s_barrier WITHOUT a
// vmcnt drain -> in-flight global loads survive the barrier (T4).
__device__ __forceinline__ void bar() {
    asm volatile("s_waitcnt lgkmcnt(0)" ::: "memory");
    __builtin_amdgcn_s_barrier();
    asm volatile("" ::: "memory");
}

// ---------------- f32 -> bf16 conversion (x, Wq, Wk, Wv, Wp) ----------------
__global__ __launch_bounds__(256) void cvt_all(
    const float* __restrict__ x, const float* __restrict__ wq,
    const float* __restrict__ wk, const float* __restrict__ wv,
    const float* __restrict__ wp,
    ushort* __restrict__ dst, ushort* __restrict__ wp_dst)
{
    const size_t flat = ((size_t)blockIdx.x * 256 + threadIdx.x) * 8;
    const float* s;
    ushort* d = dst + flat;
    size_t off;
    float scl = 1.0f;
    if (flat < (size_t)4194304)      { s = x;  off = flat; }
    else if (flat < (size_t)5242880) { s = wq; off = flat - 4194304; scl = QSCL; }
    else if (flat < (size_t)6291456) { s = wk; off = flat - 5242880; }
    else if (flat < (size_t)7340032) { s = wv; off = flat - 6291456; }
    else { s = wp; off = flat - 7340032; d = wp_dst + off; }
    const float4 a = ((const float4*)(s + off))[0];
    const float4 b = ((const float4*)(s + off))[1];
    uint4 u;
    u.x = pk2(a.x * scl, a.y * scl); u.y = pk2(a.z * scl, a.w * scl);
    u.z = pk2(b.x * scl, b.y * scl); u.w = pk2(b.z * scl, b.w * scl);
    *(uint4*)d = u;
}

// ---------------- QKV GEMM: T3/T4 pipeline + wa epilogue, NO SPILL ---------
// z=0: Q (swapped, bias*QSCL, out (B,H,S,HD))
// z=1: K (swapped, out (B,H,S,HD))
// z=2: V (unswapped, out (B,H,HD,S))
// launch_bounds(256,2): unified VGPR+AGPR cap 256 -> staging regs stay in
// registers (at (256,3)=170 they spilled to scratch: 185MB phantom writes).
__global__ __launch_bounds__(256, 2) void gemm_qkv_t34(
    const ushort* __restrict__ A,
    const ushort* __restrict__ W0, const ushort* __restrict__ W1,
    const ushort* __restrict__ W2,
    const float* __restrict__ B0, const float* __restrict__ B1,
    const float* __restrict__ B2,
    ushort* __restrict__ O0, ushort* __restrict__ O1, ushort* __restrict__ O2)
{
    __shared__ ushort As[2][128 * 32];
    __shared__ ushort Bs[2][128 * 32];
    __shared__ float bias_s[128];

    const int z = blockIdx.z;
    const ushort* W = (z == 0) ? W0 : (z == 1 ? W1 : W2);
    const float* bias = (z == 0) ? B0 : (z == 1 ? B1 : B2);
    ushort* out = (z == 0) ? O0 : (z == 1 ? O1 : O2);
    const bool isv = (z == 2);

    const int tid = threadIdx.x;
    const int bm = blockIdx.x * 128, bn = blockIdx.y * 128;
    const int wave = tid >> 6, lane = tid & 63, quad = lane >> 4, lm = lane & 15;
    const int r0 = tid >> 2, c0 = (tid & 3) * 8;
    const int c0s = ((tid & 3) ^ ((tid >> 3) & 3)) * 8;   // swizzled LDS chunk
    const int csw8 = (quad ^ ((lm >> 1) & 3)) * 8;        // swizzled read chunk

    if (tid < 128) {
        float bb = bias[bn + tid];
        if (z == 0) bb *= QSCL;
        bias_s[tid] = bb;
    }

    const floatx4 zz = {0.f, 0.f, 0.f, 0.f};
    floatx4 acc[16];
#pragma unroll
    for (int i = 0; i < 16; ++i) acc[i] = zz;

    const ushort* ap = A + (size_t)(bm + r0) * DD + c0;
    const ushort* wpp = W + (size_t)(bn + r0) * DD + c0;

    uint4 pA0, pA1, pA2, pA3, pB0, pB1, pB2, pB3;

#define LOADS(s, K0)                                              \
    do {                                                          \
        s##0 = *(const uint4*)(ap + (K0));                        \
        s##1 = *(const uint4*)(ap + (size_t)64 * DD + (K0));      \
        s##2 = *(const uint4*)(wpp + (K0));                       \
        s##3 = *(const uint4*)(wpp + (size_t)64 * DD + (K0));     \
    } while (0)
#define STORES(buf, s)                                            \
    do {                                                          \
        *(uint4*)&As[buf][r0 * 32 + c0s] = s##0;                  \
        *(uint4*)&As[buf][(64 + r0) * 32 + c0s] = s##1;           \
        *(uint4*)&Bs[buf][r0 * 32 + c0s] = s##2;                  \
        *(uint4*)&Bs[buf][(64 + r0) * 32 + c0s] = s##3;           \
    } while (0)
#define COMPUTE(buf)                                                          \
    do {                                                                      \
        if (isv) {                                                            \
            const short8 bf0 = *(const short8*)&Bs[buf][(wave * 32 + lm) * 32 + csw8];      \
            const short8 bf1 = *(const short8*)&Bs[buf][(wave * 32 + 16 + lm) * 32 + csw8]; \
            _Pragma("unroll")                                                 \
            for (int i = 0; i < 8; ++i) {                                     \
                const short8 af = *(const short8*)&As[buf][(i * 16 + lm) * 32 + csw8];      \
                acc[i * 2 + 0] = __builtin_amdgcn_mfma_f32_16x16x32_bf16(     \
                    af, bf0, acc[i * 2 + 0], 0, 0, 0);                        \
                acc[i * 2 + 1] = __builtin_amdgcn_mfma_f32_16x16x32_bf16(     \
                    af, bf1, acc[i * 2 + 1], 0, 0, 0);                        \
            }                                                                 \
        } else {                                                              \
            const short8 af0 = *(const short8*)&As[buf][(wave * 32 + lm) * 32 + csw8];      \
            const short8 af1 = *(const short8*)&As[buf][(wave * 32 + 16 + lm) * 32 + csw8]; \
            _Pragma("unroll")                                                 \
            for (int j = 0; j < 8; ++j) {                                     \
                const short8 bf = *(const short8*)&Bs[buf][(j * 16 + lm) * 32 + csw8];      \
                acc[j] = __builtin_amdgcn_mfma_f32_16x16x32_bf16(             \
                    bf, af0, acc[j], 0, 0, 0);                                \
                acc[8 + j] = __builtin_amdgcn_mfma_f32_16x16x32_bf16(         \
                    bf, af1, acc[8 + j], 0, 0, 0);                            \
            }                                                                 \
        }                                                                     \
    } while (0)

    // prologue: tile0 staged; tile1 in flight
    LOADS(pA, 0);
    STORES(0, pA);   // vmcnt(0) once
    bar();
    LOADS(pA, 32);   // tile1 in flight across barriers

    for (int k0 = 0; k0 < DD; k0 += 64) {
        if (k0 + 64 < DD) LOADS(pB, k0 + 64);   // tile+2 in flight
        COMPUTE(0);
        STORES(1, pA);                          // counted vmcnt (pB newer)
        bar();
        if (k0 + 96 < DD) LOADS(pA, k0 + 96);   // tile+3 in flight
        COMPUTE(1);
        if (k0 + 64 < DD) STORES(0, pB);        // counted vmcnt (pA newer)
        bar();
    }
#undef LOADS
#undef STORES
#undef COMPUTE

    if (isv) {
        // V: n-row per lane, 4 consecutive s per reg; 32B contiguous/instr.
        const int b = bm >> 11, sbase = bm & 2047;
#pragma unroll
        for (int j = 0; j < 2; ++j) {
            const int n = bn + wave * 32 + j * 16 + lm;
            const float bb = bias_s[n - bn];
            ushort* orow = out + ((size_t)(b * DD + n)) * SS;
#pragma unroll
            for (int i = 0; i < 8; ++i) {
                const floatx4 a = acc[i * 2 + j];
                ushort4 v;
                v.x = f2bf(a[0] + bb); v.y = f2bf(a[1] + bb);
                v.z = f2bf(a[2] + bb); v.w = f2bf(a[3] + bb);
                *(ushort4*)(orow + sbase + i * 16 + quad * 4) = v;
            }
        }
    } else {
        // Q/K: m-row per lane, 4 consecutive hd per reg; 32B contiguous/instr.
#pragma unroll
        for (int i = 0; i < 2; ++i) {
            const int m = bm + wave * 32 + i * 16 + lm;
            const int b = m >> 11, s = m & 2047;
#pragma unroll
            for (int j = 0; j < 8; ++j) {
                const int nl = j * 16 + quad * 4;
                const int n = bn + nl;
                const int h = n >> 6, hd = n & 63;
                const floatx4 a = acc[i * 8 + j];
                ushort4 v;
                v.x = f2bf(a[0] + bias_s[nl + 0]);
                v.y = f2bf(a[1] + bias_s[nl + 1]);
                v.z = f2bf(a[2] + bias_s[nl + 2]);
                v.w = f2bf(a[3] + bias_s[nl + 3]);
                *(ushort4*)(out + (((size_t)(b * HH + h) * SS) + s) * HDD + hd) = v;
            }
        }
    }
}

// ---------------- proj GEMM: 128x128, reg-staged (R18-R20 proven) ----------
__global__ __launch_bounds__(256, 2) void gemm_proj_rs(
    const ushort* __restrict__ A, const ushort* __restrict__ W,
    const float* __restrict__ bias, float* __restrict__ out)
{
    __shared__ ushort As[128 * 32];
    __shared__ ushort Bs[128 * 32];
    __shared__ float bias_s[128];

    const int tid = threadIdx.x;
    const int bm = blockIdx.x * 128, bn = blockIdx.y * 128;
    const int wave = tid >> 6, lane = tid & 63, quad = lane >> 4, lm = lane & 15;
    const int wm = wave >> 1, wn = wave & 1;
    const int r0 = tid >> 2, c0 = (tid & 3) * 8;
    const int c0s = ((tid & 3) ^ ((tid >> 3) & 3)) * 8;
    const int csw8 = (quad ^ ((lm >> 1) & 3)) * 8;

    if (tid < 128) bias_s[tid] = bias[bn + tid];

    const floatx4 zz = {0.f, 0.f, 0.f, 0.f};
    floatx4 acc[4][4];
#pragma unroll
    for (int i = 0; i < 4; ++i)
#pragma unroll
        for (int j = 0; j < 4; ++j) acc[i][j] = zz;

    const ushort* ap = A + (size_t)(bm + r0) * DD + c0;
    const ushort* wpp = W + (size_t)(bn + r0) * DD + c0;

    uint4 ar0, ar1, wr0, wr1;
#define LOADT(K0)                                                \
    do {                                                         \
        ar0 = *(const uint4*)(ap + (K0));                        \
        ar1 = *(const uint4*)(ap + (size_t)64 * DD + (K0));      \
        wr0 = *(const uint4*)(wpp + (K0));                       \
        wr1 = *(const uint4*)(wpp + (size_t)64 * DD + (K0));     \
    } while (0)
#define STORET()                                                 \
    do {                                                         \
        *(uint4*)&As[r0 * 32 + c0s] = ar0;                       \
        *(uint4*)&As[(64 + r0) * 32 + c0s] = ar1;                \
        *(uint4*)&Bs[r0 * 32 + c0s] = wr0;                       \
        *(uint4*)&Bs[(64 + r0) * 32 + c0s] = wr1;                \
    } while (0)

    LOADT(0);
    STORET();
    __syncthreads();

    for (int k0 = 0; k0 < DD; k0 += 32) {
        const bool have_nxt = (k0 + 32) < DD;
        if (have_nxt) LOADT(k0 + 32);

        short8 af[4], bf[4];
#pragma unroll
        for (int i = 0; i < 4; ++i)
            af[i] = *(const short8*)&As[(wm * 64 + i * 16 + lm) * 32 + csw8];
#pragma unroll
        for (int j = 0; j < 4; ++j)
            bf[j] = *(const short8*)&Bs[(wn * 64 + j * 16 + lm) * 32 + csw8];
#pragma unroll
        for (int i = 0; i < 4; ++i)
#pragma unroll
            for (int j = 0; j < 4; ++j)
                acc[i][j] = __builtin_amdgcn_mfma_f32_16x16x32_bf16(
                    bf[j], af[i], acc[i][j], 0, 0, 0);

        if (have_nxt) {
            __syncthreads();
            STORET();
            __syncthreads();
        }
    }
#undef LOADT
#undef STORET

#pragma unroll
    for (int i = 0; i < 4; ++i) {
#pragma unroll
        for (int j = 0; j < 4; ++j) {
            const int nl = wn * 64 + j * 16 + quad * 4;
            const int n = bn + nl;
            const int m = bm + wm * 64 + i * 16 + lm;
            float4 v;
            v.x = acc[i][j][0] + bias_s[nl + 0];
            v.y = acc[i][j][1] + bias_s[nl + 1];
            v.z = acc[i][j][2] + bias_s[nl + 2];
            v.w = acc[i][j][3] + bias_s[nl + 3];
            *(float4*)(out + (size_t)m * DD + n) = v;
        }
    }
}

// ---------------- Attention: uniform-work paired q-tiles, split-K x2 -------
__global__ __launch_bounds__(256) void attn_mfma(
    const ushort* __restrict__ Q, const ushort* __restrict__ K,
    const ushort* __restrict__ Vt, const int* __restrict__ am,
    ushort* __restrict__ Opart, float* __restrict__ lbuf)
{
    __shared__ ushort Ks[64 * 72];
    __shared__ ushort Vts[64 * 72];
    __shared__ ushort Ps[4][16 * 72];
    __shared__ int amk_s[64];

    const int tid = threadIdx.x;
    const int wq = tid >> 6, lane = tid & 63, quad = lane >> 4, lm = lane & 15;
    const int bh = blockIdx.y, b = bh >> 4, h = bh & 15;
    const int pslot = (int)blockIdx.x;   // 0..15
    const int split = (int)blockIdx.z;   // 0,1
    const size_t base = (size_t)bh * SS * HDD;
    const size_t tbase = (size_t)bh * HDD * SS;
    const int* amrow = am + b * SS;
    const int sr = tid >> 2, sc = (tid & 3) * 16;
    const floatx4 zz = {0.f, 0.f, 0.f, 0.f};

#pragma unroll
    for (int ph = 0; ph < 2; ++ph) {
        const int qt64 = ph ? (31 - pslot) : pslot;
        const int q0 = qt64 * 64;
        const int ktend = qt64;          // causal: kt*64 <= q0+63
        const int qrow = q0 + wq * 16 + lm;

        if (ph) __syncthreads();  // phase A LDS reads done before B staging

        short8 qf0, qf1;
        {
            const ushort* qp = Q + base + (size_t)qrow * HDD + quad * 8;
            qf0 = *(const short8*)qp;
            qf1 = *(const short8*)(qp + 32);
        }
        const int amq = amrow[qrow];
        const bool allq = __all(amq != 0);

        floatx4 o_acc[4];
#pragma unroll
        for (int n2 = 0; n2 < 4; ++n2) o_acc[n2] = zz;
        float l_lane = 0.f;

        if (split <= ktend) {
            // ---- prologue: stage first tile ----
            uint4 kra, krb, vra, vrb;
            int amr = 1;
            {
                const ushort* kp = K + base + (size_t)(split * 64 + sr) * HDD + sc;
                kra = ((const uint4*)kp)[0]; krb = ((const uint4*)kp)[1];
                const ushort* vp = Vt + tbase + (size_t)sr * SS + split * 64 + sc;
                vra = ((const uint4*)vp)[0]; vrb = ((const uint4*)vp)[1];
                if (tid < 64) amr = amrow[split * 64 + tid];
            }
            *(uint4*)&Ks[sr * 72 + sc] = kra;
            *(uint4*)&Ks[sr * 72 + sc + 8] = krb;
            *(uint4*)&Vts[sr * 72 + sc] = vra;
            *(uint4*)&Vts[sr * 72 + sc + 8] = vrb;
            if (tid < 64) amk_s[tid] = amr;
            __syncthreads();

            for (int kt = split; kt <= ktend; kt += 2) {
                const int nxt = kt + 2;
                const bool have_nxt = nxt <= ktend;
                // T14: issue next tile's global loads; LDS writes after barrier.
                if (have_nxt) {
                    const ushort* kp = K + base + (size_t)(nxt * 64 + sr) * HDD + sc;
                    kra = ((const uint4*)kp)[0]; krb = ((const uint4*)kp)[1];
                    const ushort* vp = Vt + tbase + (size_t)sr * SS + nxt * 64 + sc;
                    vra = ((const uint4*)vp)[0]; vrb = ((const uint4*)vp)[1];
                    if (tid < 64) amr = amrow[nxt * 64 + tid];
                }

                // ---- S^T = K Q^T (swapped): regs = 4 consecutive t ----
                const bool allk = (__ballot(amk_s[lane] != 0) == ~0ull);
                const bool fast = allk & allq & ((kt * 64 + 63) <= (q0 + wq * 16));
                if (fast) {
#pragma unroll
                    for (int nt = 0; nt < 4; ++nt) {
                        const short8 kf0 = *(const short8*)&Ks[(nt * 16 + lm) * 72 + quad * 8];
                        const short8 kf1 = *(const short8*)&Ks[(nt * 16 + lm) * 72 + 32 + quad * 8];
                        floatx4 s = zz;
                        s = __builtin_amdgcn_mfma_f32_16x16x32_bf16(kf0, qf0, s, 0, 0, 0);
                        s = __builtin_amdgcn_mfma_f32_16x16x32_bf16(kf1, qf1, s, 0, 0, 0);
                        const float e0 = exp2f(s[0]);
                        const float e1 = exp2f(s[1]);
                        const float e2 = exp2f(s[2]);
                        const float e3 = exp2f(s[3]);
                        l_lane += (e0 + e1) + (e2 + e3);
                        uint2 pv;
                        pv.x = cvtpk(e0, e1); pv.y = cvtpk(e2, e3);
                        *(uint2*)&Ps[wq][lm * 72 + nt * 16 + quad * 4] = pv;
                    }
                } else {
#pragma unroll
                    for (int nt = 0; nt < 4; ++nt) {
                        const short8 kf0 = *(const short8*)&Ks[(nt * 16 + lm) * 72 + quad * 8];
                        const short8 kf1 = *(const short8*)&Ks[(nt * 16 + lm) * 72 + 32 + quad * 8];
                        const int4 amk4 = *(const int4*)&amk_s[nt * 16 + quad * 4];
                        floatx4 s = zz;
                        s = __builtin_amdgcn_mfma_f32_16x16x32_bf16(kf0, qf0, s, 0, 0, 0);
                        s = __builtin_amdgcn_mfma_f32_16x16x32_bf16(kf1, qf1, s, 0, 0, 0);
                        const int t0 = kt * 64 + nt * 16 + quad * 4;
                        const bool mq = amq != 0;
                        const bool ok0 = amk4.x && mq && (t0 + 0 <= qrow);
                        const bool ok1 = amk4.y && mq && (t0 + 1 <= qrow);
                        const bool ok2 = amk4.z && mq && (t0 + 2 <= qrow);
                        const bool ok3 = amk4.w && mq && (t0 + 3 <= qrow);
                        const float e0 = exp2f(ok0 ? s[0] : NEG_BIG);
                        const float e1 = exp2f(ok1 ? s[1] : NEG_BIG);
                        const float e2 = exp2f(ok2 ? s[2] : NEG_BIG);
                        const float e3 = exp2f(ok3 ? s[3] : NEG_BIG);
                        l_lane += (e0 + e1) + (e2 + e3);
                        uint2 pv;
                        pv.x = cvtpk(e0, e1); pv.y = cvtpk(e2, e3);
                        *(uint2*)&Ps[wq][lm * 72 + nt * 16 + quad * 4] = pv;
                    }
                }

                // ---- O^T += V^T P^T (swapped): regs = 4 consecutive hd ----
                const short8 af0 = *(const short8*)&Ps[wq][lm * 72 + quad * 8];
                const short8 af1 = *(const short8*)&Ps[wq][lm * 72 + 32 + quad * 8];
#pragma unroll
                for (int n2 = 0; n2 < 4; ++n2) {
                    const short8 vf0 = *(const short8*)&Vts[(n2 * 16 + lm) * 72 + quad * 8];
                    const short8 vf1 = *(const short8*)&Vts[(n2 * 16 + lm) * 72 + 32 + quad * 8];
                    o_acc[n2] = __builtin_amdgcn_mfma_f32_16x16x32_bf16(
                        vf0, af0, o_acc[n2], 0, 0, 0);
                    o_acc[n2] = __builtin_amdgcn_mfma_f32_16x16x32_bf16(
                        vf1, af1, o_acc[n2], 0, 0, 0);
                }

                if (have_nxt) {
                    __syncthreads();  // all waves done reading Ks/Vts/amk_s
                    *(uint4*)&Ks[sr * 72 + sc] = kra;
                    *(uint4*)&Ks[sr * 72 + sc + 8] = krb;
                    *(uint4*)&Vts[sr * 72 + sc] = vra;
                    *(uint4*)&Vts[sr * 72 + sc + 8] = vrb;
                    if (tid < 64) amk_s[tid] = amr;
                    __syncthreads();  // next tile ready
                }
            }
        }

        // ---- epilogue: l reduce + unnormalized O ----
        float l = l_lane;
        l += __shfl_xor(l, 16);
        l += __shfl_xor(l, 32);
        if (quad == 0)
            lbuf[(size_t)split * (BB * HH * SS) + (size_t)bh * SS + qrow] = l;
#pragma unroll
        for (int n2 = 0; n2 < 4; ++n2) {
            uint2 v;
            v.x = cvtpk(o_acc[n2][0], o_acc[n2][1]);
            v.y = cvtpk(o_acc[n2][2], o_acc[n2][3]);
            *(uint2*)(Opart + (size_t)split * (BB * SS * DD)
                        + ((size_t)(b * SS + qrow)) * DD + h * HDD + n2 * 16 + quad * 4) = v;
        }
    }
}

// ---------------- combine: A = (O0 + O1) / (l0 + l1), bf16 ----------------
__global__ __launch_bounds__(256) void combine(
    const ushort* __restrict__ Opart, const float* __restrict__ lbuf,
    ushort* __restrict__ Aout)
{
    const size_t e = ((size_t)blockIdx.x * 256 + threadIdx.x) * 8;
    const int m = (int)(e >> 10);
    const int col = (int)(e & 1023);
    const int b = m >> 11, s = m & 2047, h = col >> 6;
    const float l = lbuf[(b * HH + h) * SS + s]
                  + lbuf[BB * HH * SS + (b * HH + h) * SS + s];
    const float inv = l > 0.f ? 1.f / l : 0.f;
    const uint4 u0 = *(const uint4*)(Opart + e);
    const uint4 u1 = *(const uint4*)(Opart + (size_t)BB * SS * DD + e);
    float f0[8], f1[8];
    unpack8(u0, f0);
    unpack8(u1, f1);
    uint4 o;
    o.x = pk2((f0[0] + f1[0]) * inv, (f0[1] + f1[1]) * inv);
    o.y = pk2((f0[2] + f1[2]) * inv, (f0[3] + f1[3]) * inv);
    o.z = pk2((f0[4] + f1[4]) * inv, (f0[5] + f1[5]) * inv);
    o.w = pk2((f0[6] + f1[6]) * inv, (f0[7] + f1[7]) * inv);
    *(uint4*)(Aout + e) = o;
}

extern "C" void kernel_launch(void* const* d_in, const int* in_sizes, int n_in,
                              void* d_out, int out_size, void* d_ws, size_t ws_size,
                              hipStream_t stream) {
    const float* x  = (const float*)d_in[0];
    const int*   am = (const int*)d_in[1];
    const float* Wq = (const float*)d_in[2];
    const float* bq = (const float*)d_in[3];
    const float* Wk = (const float*)d_in[4];
    const float* bk = (const float*)d_in[5];
    const float* Wv = (const float*)d_in[6];
    const float* bv = (const float*)d_in[7];
    const float* Wp = (const float*)d_in[8];
    const float* bp = (const float*)d_in[9];
    float* out = (float*)d_out;

    const size_t elems = (size_t)BB * HH * SS * HDD;  // 4M
    ushort* q_ws = (ushort*)d_ws;                 // Q; later combined A
    ushort* k_ws = q_ws + elems;
    ushort* v_ws = k_ws + elems;                  // V^T (B,H,HD,S)
    float*  lbuf = (float*)(v_ws + elems);        // 2 x 256 KB in a_ws slot
    ushort* wpb  = (ushort*)(lbuf + 2 * BB * HH * SS);  // bf16 Wp (2 MB)

    // d_out scratch: bf16 x (4M) + Wq/Wk/Wv (1M each); later attn partials
    ushort* xb  = (ushort*)d_out;
    ushort* wqb = xb + 4194304;
    ushort* wkb = wqb + 1048576;
    ushort* wvb = wkb + 1048576;

    cvt_all<<<4096, 256, 0, stream>>>(x, Wq, Wk, Wv, Wp, xb, wpb);

    gemm_qkv_t34<<<dim3(32, 8, 3), 256, 0, stream>>>(
        xb, wqb, wkb, wvb, bq, bk, bv, q_ws, k_ws, v_ws);

    attn_mfma<<<dim3(16, BB * HH, 2), 256, 0, stream>>>(
        q_ws, k_ws, v_ws, am, (ushort*)d_out, lbuf);

    combine<<<2048, 256, 0, stream>>>((const ushort*)d_out, lbuf, q_ws);

    gemm_proj_rs<<<dim3(32, 8), 256, 0, stream>>>(q_ws, wpb, bp, out);
}